// Round 6
// baseline (335.289 us; speedup 1.0000x reference)
//
#include <hip/hip_runtime.h>

#define DEV __device__ __forceinline__

typedef __attribute__((ext_vector_type(4))) float f32x4;
typedef __attribute__((ext_vector_type(8))) short short8;
typedef __attribute__((ext_vector_type(4))) short s16x4;
typedef __attribute__((ext_vector_type(4))) float f32x4v;

DEV short f2bf(float f) {
  union { float f; unsigned u; } v; v.f = f;
  unsigned r = (v.u + 0x7FFFu + ((v.u >> 16) & 1u)) >> 16;
  return (short)r;
}

DEV void gload16(const void* g, void* l) {
  __builtin_amdgcn_global_load_lds(
      (const __attribute__((address_space(1))) void*)g,
      (__attribute__((address_space(3))) void*)l, 16, 0, 0);
}

#define BAR() __builtin_amdgcn_s_barrier()
#define SB0() __builtin_amdgcn_sched_barrier(0)
#define LGKMW(n)                                              \
  {                                                           \
    asm volatile("s_waitcnt lgkmcnt(" #n ")" ::: "memory");   \
    __builtin_amdgcn_sched_barrier(0);                        \
  }
#define VMW(n)                                                \
  {                                                           \
    asm volatile("s_waitcnt vmcnt(" #n ")" ::: "memory");     \
    __builtin_amdgcn_sched_barrier(0);                        \
  }

// Load A row-quadrant qrt of buffer base B into bank AF (8 ds_read_b128).
// A region: wr=0 -> h0 (@B+0), wr=1 -> h1 (@B+8192) (rows wr*128..+127)
#define RD_A(AF, B, qrt)                                                       \
  _Pragma("unroll") for (int m_ = 0; m_ < 4; ++m_) {                           \
    AF[m_][0] = *(const short8*)&lds[(B) + aoff0 + (qrt) * 4096 + m_ * 1024];  \
    AF[m_][1] = *(const short8*)&lds[(B) + aoff1 + (qrt) * 4096 + m_ * 1024];  \
  }
// Load B col-group nh into bank BF (4 ds_read_b128).
// Region-correct mapping: nh selects the HALF-REGION (h0 @+16384, h1 @+24576)
// for ALL waves; wave wc owns col' = n_*64 + wc*16 + l15 within the region.
#define RD_B(BF, B, nh)                                                          \
  _Pragma("unroll") for (int n_ = 0; n_ < 2; ++n_) {                             \
    BF[n_][0] = *(const short8*)&lds[(B) + 16384 + (nh) * 8192 + n_ * 4096 +     \
                                     boff0];                                     \
    BF[n_][1] = *(const short8*)&lds[(B) + 16384 + (nh) * 8192 + n_ * 4096 +     \
                                     boff1];                                     \
  }
// Swapped operand order: D = mfma(bf, af) -> C row = l15, C col = l4*4 + reg
// acc col fragment n = nh*2+n_ -> global col (n>>1)*128 + (n&1)*64 + wc*16 + l4*4 + reg
#define MFMA_Q(mq, nh, AF, BF)                                                   \
  __builtin_amdgcn_s_setprio(1);                                                 \
  _Pragma("unroll") for (int m_ = 0; m_ < 4; ++m_) {                             \
    _Pragma("unroll") for (int n_ = 0; n_ < 2; ++n_) {                           \
      acc[(mq) * 4 + m_][(nh) * 2 + n_] =                                        \
          __builtin_amdgcn_mfma_f32_16x16x32_bf16(                               \
              BF[n_][0], AF[m_][0], acc[(mq) * 4 + m_][(nh) * 2 + n_], 0, 0, 0); \
      acc[(mq) * 4 + m_][(nh) * 2 + n_] =                                        \
          __builtin_amdgcn_mfma_f32_16x16x32_bf16(                               \
              BF[n_][1], AF[m_][1], acc[(mq) * 4 + m_][(nh) * 2 + n_], 0, 0, 0); \
    }                                                                            \
  }                                                                              \
  __builtin_amdgcn_s_setprio(0);

struct FullTag { static constexpr bool value = true; };
struct LastTag { static constexpr bool value = false; };

// ---------------- prep kernels ----------------

__global__ __launch_bounds__(256) void k_prep_keys(const float* __restrict__ k,
                                                   short* __restrict__ o) {
  int i = (blockIdx.x * 256 + threadIdx.x) * 8;
  f32x4v v0 = *(const f32x4v*)(k + i);
  f32x4v v1 = *(const f32x4v*)(k + i + 4);
  short8 s;
  s[0] = f2bf(v0[0]); s[1] = f2bf(v0[1]); s[2] = f2bf(v0[2]); s[3] = f2bf(v0[3]);
  s[4] = f2bf(v1[0]); s[5] = f2bf(v1[1]); s[6] = f2bf(v1[2]); s[7] = f2bf(v1[3]);
  *(short8*)(o + i) = s;
}

// W2 [k][n] f32 -> W2t [n][k] bf16
__global__ __launch_bounds__(256) void k_prep_w2t(const float* __restrict__ w2,
                                                  short* __restrict__ w2t) {
  __shared__ float tile[64][65];
  const int k0 = blockIdx.x * 64, n0 = blockIdx.y * 64;
  const int a = threadIdx.x & 63, q = threadIdx.x >> 6;
#pragma unroll
  for (int i = 0; i < 16; ++i) {
    int kk = i * 4 + q;
    tile[kk][a] = w2[(size_t)(k0 + kk) * 1024 + n0 + a];
  }
  __syncthreads();
#pragma unroll
  for (int i = 0; i < 16; ++i) {
    int nn = i * 4 + q;
    w2t[(size_t)(n0 + nn) * 1024 + k0 + a] = f2bf(tile[a][nn]);
  }
}

// Wkt[b][d][m] = bf16( W1[256+m][d] - W1[512+m][d] + q[b][m]*W1[768+m][d] )
// + fused bias: biasb[b][d] = b1[d] + sum_m q[b][m]*(W1[m][d] + W1[512+m][d])
__global__ __launch_bounds__(256) void k_prep_wkt(const float* __restrict__ w1,
                                                  const float* __restrict__ query,
                                                  const float* __restrict__ b1,
                                                  short* __restrict__ wkt,
                                                  float* __restrict__ biasb) {
  __shared__ short tile[64][257];
  __shared__ float redm[64][4];
  const int b = blockIdx.x, d0 = blockIdx.y * 64;
  const int d = threadIdx.x & 63, mq = threadIdx.x >> 6;
  float bacc = 0.f;
#pragma unroll 4
  for (int i = 0; i < 64; ++i) {
    int m = i * 4 + mq;
    float qv = query[b * 256 + m];
    float wa = w1[(size_t)m * 1024 + d0 + d];
    float wb = w1[(size_t)(256 + m) * 1024 + d0 + d];
    float wc = w1[(size_t)(512 + m) * 1024 + d0 + d];
    float wd = w1[(size_t)(768 + m) * 1024 + d0 + d];
    tile[d][m] = f2bf(wb - wc + qv * wd);
    bacc += qv * (wa + wc);
  }
  redm[d][mq] = bacc;
  __syncthreads();
  const int m = threadIdx.x;
  for (int dd = 0; dd < 64; ++dd)
    wkt[((size_t)b * 1024 + d0 + dd) * 256 + m] = tile[dd][m];
  if (threadIdx.x < 64) {
    int dd = threadIdx.x;
    biasb[b * 1024 + d0 + dd] =
        redm[dd][0] + redm[dd][1] + redm[dd][2] + redm[dd][3] + b1[d0 + dd];
  }
}

// ---------------- 8-phase pipelined 256x256 GEMM (TN) ----------------
// Register-fragment double-buffering: reads for phase i+1 issued at phase i,
// one barrier per phase, counted vmcnt publication:
//   stages: S1 Bq.h0@f0, S2 Bq.h1@f1, S3 Ap.h0@f2, S4 Ap.h1@f3,
//           S5 Bp.h0@f4, S6 Bp.h1@f5, S7 Aq.h0@f6, S8 Aq.h1@f7
//   VMW(6)@f0, VMW(4)@f2, VMW(6)@f4, VMW(4)@f6  (steady state)
// Read->stage drain audit (steady state, all waves):
//   f1 rd Bp.h1=S6(2 bodies back, drained f0) | f3 rd Bq.h0=S1(drained f2 VMW4),
//   Aq.h0=S7/Aq.h1=S8 (drained f2) | f4 rd Aq=S7/S8 ok | f5 rd Bq.h1=S2
//   (drained f4 VMW6) | f7 rd Bp.h0=S5 (drained f6 VMW4), Ap.h0=S3/Ap.h1=S4
//   (drained f6).

template <int MODE>
__global__ __launch_bounds__(512) void k_gemm8(const short* __restrict__ A,
                                               const short* __restrict__ B,
                                               const float* __restrict__ bias,
                                               const float* __restrict__ wscore,
                                               short* __restrict__ hout,
                                               float* __restrict__ spart) {
  __shared__ short lds[65536];  // buf p @0, buf q @32768; {A0,A1,B0,B1} x 8192 shorts
  constexpr int SK = (MODE == 1) ? 256 : 1024;
  constexpr int KT = (MODE == 1) ? 4 : 16;
  constexpr int P = 0, Q = 32768;

  const int tid = threadIdx.x;
  const int bx = blockIdx.x;
  const int L = (bx & 7) * 128 + (bx >> 3);  // XCD-bijective swizzle (1024%8==0)

  const short *Ab, *Bb;
  const float *biasp, *wsp = nullptr;
  short* houtp = nullptr;
  int rt, ct;
  if constexpr (MODE == 1) {
    const int b = L >> 4;
    rt = (L >> 2) & 3; ct = L & 3;
    Ab = A + ((size_t)b * 1024 + rt * 256) * 256;
    Bb = B + ((size_t)b * 1024 + ct * 256) * 256;
    biasp = bias + b * 1024 + ct * 256;
    houtp = hout + ((size_t)(b * 1024 + rt * 256)) * 1024 + ct * 256;
  } else {
    rt = L >> 2; ct = L & 3;
    Ab = A + (size_t)rt * 256 * 1024;
    Bb = B + (size_t)ct * 256 * 1024;
    biasp = bias + ct * 256;
    wsp = wscore + ct * 256;
  }

  // staging: chunk c -> row=c>>3, slot=c&7, src k16 = slot^(row&7)
  const int c0 = tid, c1 = 512 + tid;
  const int r0 = c0 >> 3, k0 = ((c0 & 7) ^ (r0 & 7)) * 8;
  const int r1 = c1 >> 3, k1 = ((c1 & 7) ^ (r1 & 7)) * 8;

  auto STAGE = [&](const short* gb, int kt, int half, int ldsb) {
    gload16(gb + (size_t)(half * 128 + r0) * SK + kt * 64 + k0, &lds[ldsb + c0 * 8]);
    gload16(gb + (size_t)(half * 128 + r1) * SK + kt * 64 + k1, &lds[ldsb + c1 * 8]);
  };

  // fragment-read constants
  const int lane = tid & 63, l15 = lane & 15, l4 = lane >> 4;
  const int wid = tid >> 6, wr = wid >> 2, wc = wid & 3;
  const int aoff0 = wr * 8192 + l15 * 64 + ((l4 ^ (l15 & 7)) * 8);
  const int aoff1 = wr * 8192 + l15 * 64 + (((4 + l4) ^ (l15 & 7)) * 8);
  // B col within region: col' = n_*64 + wc*16 + l15  (region picked by nh)
  const int boff0 = wc * 1024 + l15 * 64 + ((l4 ^ (l15 & 7)) * 8);
  const int boff1 = wc * 1024 + l15 * 64 + (((4 + l4) ^ (l15 & 7)) * 8);

  f32x4 acc[8][4];
#pragma unroll
  for (int m = 0; m < 8; ++m)
#pragma unroll
    for (int n = 0; n < 4; ++n) acc[m][n] = f32x4{0.f, 0.f, 0.f, 0.f};
  short8 afA[4][2], afB[4][2];  // A row-quad banks
  short8 bfA[2][2], bfB[2][2];  // B col-group banks

  // prologue: stage p(t0) full + q(t1) A; drain all; preload afA,afB,bfA
  STAGE(Ab, 0, 0, P + 0);
  STAGE(Ab, 0, 1, P + 8192);
  STAGE(Bb, 0, 0, P + 16384);
  STAGE(Bb, 0, 1, P + 24576);
  STAGE(Ab, 1, 0, Q + 0);
  STAGE(Ab, 1, 1, Q + 8192);
  VMW(0);
  BAR();
  RD_A(afA, P, 0);
  RD_A(afB, P, 1);
  RD_B(bfA, P, 0);

  auto body = [&](int t, auto tag) {
    constexpr bool FULL = decltype(tag)::value;
    // f0
    LGKMW(0);
    MFMA_Q(0, 0, afA, bfA);
    STAGE(Bb, t + 1, 0, Q + 16384);          // S1
    VMW(6);
    BAR();
    // f1
    RD_B(bfB, P, 1);
    SB0();
    MFMA_Q(1, 0, afB, bfA);
    STAGE(Bb, t + 1, 1, Q + 24576);          // S2
    BAR();
    // f2
    LGKMW(0);
    MFMA_Q(1, 1, afB, bfB);
    if constexpr (FULL) STAGE(Ab, t + 2, 0, P + 0);  // S3
    if constexpr (FULL) { VMW(4); } else { VMW(2); }
    BAR();
    // f3
    RD_B(bfA, Q, 0);
    SB0();
    MFMA_Q(0, 1, afA, bfB);
    RD_A(afA, Q, 0);                          // post-MFMA reload
    if constexpr (FULL) STAGE(Ab, t + 2, 1, P + 8192);  // S4
    BAR();
    // f4
    LGKMW(0);
    RD_A(afB, Q, 1);
    SB0();
    MFMA_Q(0, 0, afA, bfA);
    if constexpr (FULL) STAGE(Bb, t + 2, 0, P + 16384);  // S5
    if constexpr (FULL) { VMW(6); } else { VMW(0); }
    BAR();
    // f5
    LGKMW(0);
    RD_B(bfB, Q, 1);
    SB0();
    MFMA_Q(1, 0, afB, bfA);
    if constexpr (FULL) STAGE(Bb, t + 2, 1, P + 24576);  // S6
    BAR();
    // f6
    LGKMW(0);
    MFMA_Q(1, 1, afB, bfB);
    if constexpr (FULL) STAGE(Ab, t + 3, 0, Q + 0);      // S7
    if constexpr (FULL) VMW(4);
    BAR();
    // f7
    if constexpr (FULL) {
      RD_B(bfA, P, 0);
      RD_A(afB, P, 1);
      SB0();
    }
    MFMA_Q(0, 1, afA, bfB);
    if constexpr (FULL) {
      RD_A(afA, P, 0);                        // post-MFMA reload
      STAGE(Ab, t + 3, 1, Q + 8192);          // S8
      BAR();
    }
  };

#pragma nounroll
  for (int i = 0; i < KT / 2 - 1; ++i) body(2 * i, FullTag{});
  body(KT - 2, LastTag{});

  // ---------------- epilogue ----------------
  // C^T fragments: row = wr*128 + m*16 + l15,
  // col(n,r2) = (n>>1)*128 + (n&1)*64 + wc*16 + l4*4 + r2
  if constexpr (MODE == 1) {
    float bv[4][4];
#pragma unroll
    for (int n = 0; n < 4; ++n)
#pragma unroll
      for (int r2 = 0; r2 < 4; ++r2)
        bv[n][r2] = biasp[(n >> 1) * 128 + (n & 1) * 64 + wc * 16 + l4 * 4 + r2];
#pragma unroll
    for (int m = 0; m < 8; ++m) {
      int row = wr * 128 + m * 16 + l15;
#pragma unroll
      for (int n = 0; n < 4; ++n) {
        s16x4 pk;
#pragma unroll
        for (int r2 = 0; r2 < 4; ++r2)
          pk[r2] = f2bf(fmaxf(acc[m][n][r2] + bv[n][r2], 0.f));
        *(s16x4*)&houtp[(size_t)row * 1024 + (n >> 1) * 128 + (n & 1) * 64 +
                        wc * 16 + l4 * 4] = pk;
      }
    }
  } else {
    float bv[4][4], wv[4][4];
#pragma unroll
    for (int n = 0; n < 4; ++n)
#pragma unroll
      for (int r2 = 0; r2 < 4; ++r2) {
        int c = (n >> 1) * 128 + (n & 1) * 64 + wc * 16 + l4 * 4 + r2;
        bv[n][r2] = biasp[c];
        wv[n][r2] = wsp[c];
      }
    float* so = spart + ((size_t)(ct * 4 + wc) << 16) + rt * 256 + wr * 128;
#pragma unroll
    for (int m = 0; m < 8; ++m) {
      float s = 0.f;
#pragma unroll
      for (int n = 0; n < 4; ++n)
#pragma unroll
        for (int r2 = 0; r2 < 4; ++r2)
          s += fmaxf(acc[m][n][r2] + bv[n][r2], 0.f) * wv[n][r2];
      s += __shfl_xor(s, 16);
      s += __shfl_xor(s, 32);
      if (lane < 16) so[m * 16 + l15] = s;
    }
  }
}

// ---------------- softmax + output ----------------

__global__ __launch_bounds__(256) void k_softmax(const float* __restrict__ spart,
                                                 const float* __restrict__ mask,
                                                 const float* __restrict__ bscore,
                                                 float* __restrict__ attn) {
  const int b = blockIdx.x, tid = threadIdx.x;
  __shared__ float sm[1024];
  __shared__ float red[8];
  const float bs = bscore[0];
  float lmax = -3.0e38f;
  for (int t = tid; t < 1024; t += 256) {
    float s = bs;
#pragma unroll
    for (int c = 0; c < 16; ++c) s += spart[(size_t)c * 65536 + b * 1024 + t];
    float lg = s + mask[b * 1024 + t] * (-1e9f);
    sm[t] = lg;
    lmax = fmaxf(lmax, lg);
  }
  for (int o = 32; o; o >>= 1) lmax = fmaxf(lmax, __shfl_xor(lmax, o));
  const int wid = tid >> 6, lane = tid & 63;
  if (lane == 0) red[wid] = lmax;
  __syncthreads();
  float bmax = fmaxf(fmaxf(red[0], red[1]), fmaxf(red[2], red[3]));
  float lsum = 0.f;
  for (int t = tid; t < 1024; t += 256) {
    float e = __expf(sm[t] - bmax);
    sm[t] = e;
    lsum += e;
  }
  for (int o = 32; o; o >>= 1) lsum += __shfl_xor(lsum, o);
  __syncthreads();
  if (lane == 0) red[wid] = lsum;
  __syncthreads();
  float inv = 1.0f / (red[0] + red[1] + red[2] + red[3]);
  for (int t = tid; t < 1024; t += 256) attn[b * 1024 + t] = sm[t] * inv;
}

// out partials: block (b, ts): sum t in [ts*128, ts*128+128) over all 1024 d
__global__ __launch_bounds__(256) void k_out(const float* __restrict__ attn,
                                             const float* __restrict__ values,
                                             float* __restrict__ part) {
  const int b = blockIdx.x >> 3, ts = blockIdx.x & 7;
  const int tid = threadIdx.x;
  __shared__ float at[128];
  if (tid < 128) at[tid] = attn[b * 1024 + ts * 128 + tid];
  __syncthreads();
  const float* vb = values + ((size_t)b * 1024 + ts * 128) * 1024 + tid * 4;
  f32x4 acc = {0.f, 0.f, 0.f, 0.f};
#pragma unroll 8
  for (int t = 0; t < 128; ++t) {
    f32x4v v = *(const f32x4v*)(vb + (size_t)t * 1024);
    float a = at[t];
    acc[0] += a * v[0]; acc[1] += a * v[1]; acc[2] += a * v[2]; acc[3] += a * v[3];
  }
  *(f32x4*)(part + ((size_t)(b * 8 + ts)) * 1024 + tid * 4) = acc;
}

__global__ __launch_bounds__(256) void k_red(const float* __restrict__ part,
                                             float* __restrict__ out) {
  const int b = blockIdx.x;
  const int c4 = threadIdx.x * 4;
  f32x4 s = {0.f, 0.f, 0.f, 0.f};
#pragma unroll
  for (int ts = 0; ts < 8; ++ts) {
    f32x4v v = *(const f32x4v*)(part + ((size_t)(b * 8 + ts)) * 1024 + c4);
    s[0] += v[0]; s[1] += v[1]; s[2] += v[2]; s[3] += v[3];
  }
  *(f32x4*)(out + b * 1024 + c4) = s;
}

// ---------------- launch ----------------

extern "C" void kernel_launch(void* const* d_in, const int* in_sizes, int n_in,
                              void* d_out, int out_size, void* d_ws, size_t ws_size,
                              hipStream_t stream) {
  const float* query  = (const float*)d_in[0];
  const float* keys   = (const float*)d_in[1];
  const float* values = (const float*)d_in[2];
  const float* mask   = (const float*)d_in[3];
  const float* W1     = (const float*)d_in[4];
  const float* b1     = (const float*)d_in[5];
  const float* W2     = (const float*)d_in[6];
  const float* b2     = (const float*)d_in[7];
  const float* wscore = (const float*)d_in[8];
  const float* bscore = (const float*)d_in[9];
  float* out = (float*)d_out;

  char* ws = (char*)d_ws;
  short* keysb = (short*)(ws);                   // 33,554,432 B
  short* wkt   = (short*)(ws + 33554432ull);     // 33,554,432 B
  short* w2t   = (short*)(ws + 67108864ull);     //  2,097,152 B
  float* biasb = (float*)(ws + 69206016ull);     //    262,144 B
  short* h1    = (short*)(ws + 69468160ull);     // 134,217,728 B
  float* spart = (float*)(ws + 203685888ull);    //  4,194,304 B
  float* attn  = (float*)(ws + 207880192ull);    //    262,144 B
  float* part  = (float*)(ws + 208142336ull);    //  2,097,152 B (total ~210 MB)

  k_prep_keys<<<8192, 256, 0, stream>>>(keys, keysb);
  k_prep_w2t<<<dim3(16, 16), 256, 0, stream>>>(W2, w2t);
  k_prep_wkt<<<dim3(64, 16), 256, 0, stream>>>(W1, query, b1, wkt, biasb);

  k_gemm8<1><<<1024, 512, 0, stream>>>(keysb, wkt, biasb, nullptr, h1, nullptr);
  k_gemm8<2><<<1024, 512, 0, stream>>>(h1, w2t, b2, wscore, nullptr, spart);

  k_softmax<<<64, 256, 0, stream>>>(spart, mask, bscore, attn);
  k_out<<<512, 256, 0, stream>>>(attn, values, part);
  k_red<<<64, 256, 0, stream>>>(part, out);
}

// Round 7
// 293.254 us; speedup vs baseline: 1.1433x; 1.1433x over previous
//
#include <hip/hip_runtime.h>

#define DEV __device__ __forceinline__

typedef __attribute__((ext_vector_type(4))) float f32x4;
typedef __attribute__((ext_vector_type(8))) short short8;
typedef __attribute__((ext_vector_type(4))) short s16x4;
typedef __attribute__((ext_vector_type(4))) float f32x4v;

DEV short f2bf(float f) {
  union { float f; unsigned u; } v; v.f = f;
  unsigned r = (v.u + 0x7FFFu + ((v.u >> 16) & 1u)) >> 16;
  return (short)r;
}

DEV void gload16(const void* g, void* l) {
  __builtin_amdgcn_global_load_lds(
      (const __attribute__((address_space(1))) void*)g,
      (__attribute__((address_space(3))) void*)l, 16, 0, 0);
}

#define BAR() __builtin_amdgcn_s_barrier()
#define LGKMW(n)                                              \
  {                                                           \
    asm volatile("s_waitcnt lgkmcnt(" #n ")" ::: "memory");   \
    __builtin_amdgcn_sched_barrier(0);                        \
  }
#define VMW(n)                                                \
  {                                                           \
    asm volatile("s_waitcnt vmcnt(" #n ")" ::: "memory");     \
    __builtin_amdgcn_sched_barrier(0);                        \
  }

// ---------------- prep kernels ----------------

__global__ __launch_bounds__(256) void k_prep_keys(const float* __restrict__ k,
                                                   short* __restrict__ o) {
  int i = (blockIdx.x * 256 + threadIdx.x) * 8;
  f32x4v v0 = *(const f32x4v*)(k + i);
  f32x4v v1 = *(const f32x4v*)(k + i + 4);
  short8 s;
  s[0] = f2bf(v0[0]); s[1] = f2bf(v0[1]); s[2] = f2bf(v0[2]); s[3] = f2bf(v0[3]);
  s[4] = f2bf(v1[0]); s[5] = f2bf(v1[1]); s[6] = f2bf(v1[2]); s[7] = f2bf(v1[3]);
  *(short8*)(o + i) = s;
}

// W2 [k][n] f32 -> W2t [n][k] bf16
__global__ __launch_bounds__(256) void k_prep_w2t(const float* __restrict__ w2,
                                                  short* __restrict__ w2t) {
  __shared__ float tile[64][65];
  const int k0 = blockIdx.x * 64, n0 = blockIdx.y * 64;
  const int a = threadIdx.x & 63, q = threadIdx.x >> 6;
#pragma unroll
  for (int i = 0; i < 16; ++i) {
    int kk = i * 4 + q;
    tile[kk][a] = w2[(size_t)(k0 + kk) * 1024 + n0 + a];
  }
  __syncthreads();
#pragma unroll
  for (int i = 0; i < 16; ++i) {
    int nn = i * 4 + q;
    w2t[(size_t)(n0 + nn) * 1024 + k0 + a] = f2bf(tile[a][nn]);
  }
}

// Wkt[b][d][m] = bf16( W1[256+m][d] - W1[512+m][d] + q[b][m]*W1[768+m][d] )
// + fused bias: biasb[b][d] = b1[d] + sum_m q[b][m]*(W1[m][d] + W1[512+m][d])
__global__ __launch_bounds__(256) void k_prep_wkt(const float* __restrict__ w1,
                                                  const float* __restrict__ query,
                                                  const float* __restrict__ b1,
                                                  short* __restrict__ wkt,
                                                  float* __restrict__ biasb) {
  __shared__ short tile[64][257];
  __shared__ float redm[64][4];
  const int b = blockIdx.x, d0 = blockIdx.y * 64;
  const int d = threadIdx.x & 63, mq = threadIdx.x >> 6;
  float bacc = 0.f;
#pragma unroll 4
  for (int i = 0; i < 64; ++i) {
    int m = i * 4 + mq;
    float qv = query[b * 256 + m];
    float wa = w1[(size_t)m * 1024 + d0 + d];
    float wb = w1[(size_t)(256 + m) * 1024 + d0 + d];
    float wc = w1[(size_t)(512 + m) * 1024 + d0 + d];
    float wd = w1[(size_t)(768 + m) * 1024 + d0 + d];
    tile[d][m] = f2bf(wb - wc + qv * wd);
    bacc += qv * (wa + wc);
  }
  redm[d][mq] = bacc;
  __syncthreads();
  const int m = threadIdx.x;
  for (int dd = 0; dd < 64; ++dd)
    wkt[((size_t)b * 1024 + d0 + dd) * 256 + m] = tile[dd][m];
  if (threadIdx.x < 64) {
    int dd = threadIdx.x;
    biasb[b * 1024 + d0 + dd] =
        redm[dd][0] + redm[dd][1] + redm[dd][2] + redm[dd][3] + b1[d0 + dd];
  }
}

// ---------------- 2-block/CU GEMM (TN: C[i][j] = sum_k A[i][k]*B[j][k]) ------
// BM=128, BN=256, BK=32, 256 thr (4 waves 1Mx4N), LDS 48 KiB double-buffered
// -> 2 blocks/CU (launch_bounds(256,2)). Cross-block TLP hides per-phase
// read-burst/MFMA-burst serialization that pinned the 512-thr kernel at 38%.
// Swizzle (BK=32, 64B rows): chunk slot = c ^ ((row>>1)&3); 2-way conflicts
// on ds_read_b128 (free per m136). Per K-step: 12 ds_read_b128 + 32 indep MFMA.
// MODE 1: per-batch keys@Wk + bias, relu -> h1 (bf16).  K=256 (KT=8).
// MODE 2: h1@W2t + b2, relu, dot w_score -> score partials. K=1024 (KT=32).

template <int MODE>
__global__ __launch_bounds__(256, 2) void k_gemm(const short* __restrict__ A,
                                                 const short* __restrict__ B,
                                                 const float* __restrict__ bias,
                                                 const float* __restrict__ wscore,
                                                 short* __restrict__ hout,
                                                 float* __restrict__ spart) {
  __shared__ short lds[24576];  // buf0 @0, buf1 @12288; per buf: A 4096, B 8192
  constexpr int SK = (MODE == 1) ? 256 : 1024;
  constexpr int KT = (MODE == 1) ? 8 : 32;

  const int tid = threadIdx.x;
  const int bx = blockIdx.x;
  const int L = (bx & 7) * 256 + (bx >> 3);  // XCD-bijective swizzle (2048%8==0)

  const short *Ab, *Bb;
  const float *biasp, *wsp = nullptr;
  short* houtp = nullptr;
  int rt, ct;
  if constexpr (MODE == 1) {
    const int b = L >> 5;
    rt = (L >> 2) & 7; ct = L & 3;
    Ab = A + ((size_t)b * 1024 + rt * 128) * 256;
    Bb = B + ((size_t)b * 1024 + ct * 256) * 256;
    biasp = bias + b * 1024 + ct * 256;
    houtp = hout + ((size_t)(b * 1024 + rt * 128)) * 1024 + ct * 256;
  } else {
    rt = L >> 2; ct = L & 3;
    Ab = A + (size_t)rt * 128 * 1024;
    Bb = B + (size_t)ct * 256 * 1024;
    biasp = bias + ct * 256;
    wsp = wscore + ct * 256;
  }

  // staging: chunk s -> row = s>>2, slot = s&3, src k-chunk c = slot^((row>>1)&3)
  int gA[2], dA[2], gB[4], dB[4];
#pragma unroll
  for (int j = 0; j < 2; ++j) {
    int s = tid + j * 256, row = s >> 2, c = (s & 3) ^ ((row >> 1) & 3);
    gA[j] = row * SK + c * 8;
    dA[j] = s * 8;
  }
#pragma unroll
  for (int j = 0; j < 4; ++j) {
    int s = tid + j * 256, row = s >> 2, c = (s & 3) ^ ((row >> 1) & 3);
    gB[j] = row * SK + c * 8;
    dB[j] = 4096 + s * 8;
  }

  auto STAGE = [&](int kt, int buf) {
#pragma unroll
    for (int j = 0; j < 2; ++j) gload16(Ab + gA[j] + kt * 32, &lds[buf + dA[j]]);
#pragma unroll
    for (int j = 0; j < 4; ++j) gload16(Bb + gB[j] + kt * 32, &lds[buf + dB[j]]);
  };

  // fragment-read constants
  const int lane = tid & 63, l15 = lane & 15, l4 = lane >> 4, wc = tid >> 6;
  const int swz = (l4 ^ ((l15 >> 1) & 3)) * 8;
  const int aoff = l15 * 32 + swz;
  const int boff = 4096 + wc * 512 + l15 * 32 + swz;

  f32x4 acc[8][4];
#pragma unroll
  for (int m = 0; m < 8; ++m)
#pragma unroll
    for (int n = 0; n < 4; ++n) acc[m][n] = f32x4{0.f, 0.f, 0.f, 0.f};

  STAGE(0, 0);
#pragma unroll 2
  for (int kt = 0; kt < KT; ++kt) {
    const int cur = (kt & 1) * 12288;
    if (kt + 1 < KT) {
      STAGE(kt + 1, 12288 - cur);
      VMW(6);           // drain prev stage (6), keep this stage's 6 in flight
    } else {
      VMW(0);
    }
    BAR();              // buf[cur] visible to all waves
    short8 af[8], bf[4];
#pragma unroll
    for (int m = 0; m < 8; ++m) af[m] = *(const short8*)&lds[cur + aoff + m * 512];
#pragma unroll
    for (int n = 0; n < 4; ++n) bf[n] = *(const short8*)&lds[cur + boff + n * 2048];
    LGKMW(0);
    BAR();              // all waves done reading buf[cur] -> next stage may overwrite
    __builtin_amdgcn_s_setprio(1);
#pragma unroll
    for (int m = 0; m < 8; ++m)
#pragma unroll
      for (int n = 0; n < 4; ++n)
        acc[m][n] = __builtin_amdgcn_mfma_f32_16x16x32_bf16(bf[n], af[m],
                                                            acc[m][n], 0, 0, 0);
    __builtin_amdgcn_s_setprio(0);
  }

  // ---------------- epilogue ----------------
  // C fragments: row = m*16 + l15, col(n,r2) = n*64 + wc*16 + l4*4 + r2
  if constexpr (MODE == 1) {
    float bv[4][4];
#pragma unroll
    for (int n = 0; n < 4; ++n)
#pragma unroll
      for (int r2 = 0; r2 < 4; ++r2)
        bv[n][r2] = biasp[n * 64 + wc * 16 + l4 * 4 + r2];
#pragma unroll
    for (int m = 0; m < 8; ++m) {
      int row = m * 16 + l15;
#pragma unroll
      for (int n = 0; n < 4; ++n) {
        s16x4 pk;
#pragma unroll
        for (int r2 = 0; r2 < 4; ++r2)
          pk[r2] = f2bf(fmaxf(acc[m][n][r2] + bv[n][r2], 0.f));
        *(s16x4*)&houtp[(size_t)row * 1024 + n * 64 + wc * 16 + l4 * 4] = pk;
      }
    }
  } else {
    float bv[4][4], wv[4][4];
#pragma unroll
    for (int n = 0; n < 4; ++n)
#pragma unroll
      for (int r2 = 0; r2 < 4; ++r2) {
        int c = n * 64 + wc * 16 + l4 * 4 + r2;
        bv[n][r2] = biasp[c];
        wv[n][r2] = wsp[c];
      }
    float* so = spart + ((size_t)(ct * 4 + wc) << 16) + rt * 128;
#pragma unroll
    for (int m = 0; m < 8; ++m) {
      float s = 0.f;
#pragma unroll
      for (int n = 0; n < 4; ++n)
#pragma unroll
        for (int r2 = 0; r2 < 4; ++r2)
          s += fmaxf(acc[m][n][r2] + bv[n][r2], 0.f) * wv[n][r2];
      s += __shfl_xor(s, 16);
      s += __shfl_xor(s, 32);
      if (lane < 16) so[m * 16 + l15] = s;
    }
  }
}

// ---------------- softmax + output ----------------

__global__ __launch_bounds__(256) void k_softmax(const float* __restrict__ spart,
                                                 const float* __restrict__ mask,
                                                 const float* __restrict__ bscore,
                                                 float* __restrict__ attn) {
  const int b = blockIdx.x, tid = threadIdx.x;
  __shared__ float sm[1024];
  __shared__ float red[8];
  const float bs = bscore[0];
  float lmax = -3.0e38f;
  for (int t = tid; t < 1024; t += 256) {
    float s = bs;
#pragma unroll
    for (int c = 0; c < 16; ++c) s += spart[(size_t)c * 65536 + b * 1024 + t];
    float lg = s + mask[b * 1024 + t] * (-1e9f);
    sm[t] = lg;
    lmax = fmaxf(lmax, lg);
  }
  for (int o = 32; o; o >>= 1) lmax = fmaxf(lmax, __shfl_xor(lmax, o));
  const int wid = tid >> 6, lane = tid & 63;
  if (lane == 0) red[wid] = lmax;
  __syncthreads();
  float bmax = fmaxf(fmaxf(red[0], red[1]), fmaxf(red[2], red[3]));
  float lsum = 0.f;
  for (int t = tid; t < 1024; t += 256) {
    float e = __expf(sm[t] - bmax);
    sm[t] = e;
    lsum += e;
  }
  for (int o = 32; o; o >>= 1) lsum += __shfl_xor(lsum, o);
  __syncthreads();
  if (lane == 0) red[wid] = lsum;
  __syncthreads();
  float inv = 1.0f / (red[0] + red[1] + red[2] + red[3]);
  for (int t = tid; t < 1024; t += 256) attn[b * 1024 + t] = sm[t] * inv;
}

// out partials: block (b, ts): sum t in [ts*128, ts*128+128) over all 1024 d
__global__ __launch_bounds__(256) void k_out(const float* __restrict__ attn,
                                             const float* __restrict__ values,
                                             float* __restrict__ part) {
  const int b = blockIdx.x >> 3, ts = blockIdx.x & 7;
  const int tid = threadIdx.x;
  __shared__ float at[128];
  if (tid < 128) at[tid] = attn[b * 1024 + ts * 128 + tid];
  __syncthreads();
  const float* vb = values + ((size_t)b * 1024 + ts * 128) * 1024 + tid * 4;
  f32x4 acc = {0.f, 0.f, 0.f, 0.f};
#pragma unroll 8
  for (int t = 0; t < 128; ++t) {
    f32x4v v = *(const f32x4v*)(vb + (size_t)t * 1024);
    float a = at[t];
    acc[0] += a * v[0]; acc[1] += a * v[1]; acc[2] += a * v[2]; acc[3] += a * v[3];
  }
  *(f32x4*)(part + ((size_t)(b * 8 + ts)) * 1024 + tid * 4) = acc;
}

__global__ __launch_bounds__(256) void k_red(const float* __restrict__ part,
                                             float* __restrict__ out) {
  const int b = blockIdx.x;
  const int c4 = threadIdx.x * 4;
  f32x4 s = {0.f, 0.f, 0.f, 0.f};
#pragma unroll
  for (int ts = 0; ts < 8; ++ts) {
    f32x4v v = *(const f32x4v*)(part + ((size_t)(b * 8 + ts)) * 1024 + c4);
    s[0] += v[0]; s[1] += v[1]; s[2] += v[2]; s[3] += v[3];
  }
  *(f32x4*)(out + b * 1024 + c4) = s;
}

// ---------------- launch ----------------

extern "C" void kernel_launch(void* const* d_in, const int* in_sizes, int n_in,
                              void* d_out, int out_size, void* d_ws, size_t ws_size,
                              hipStream_t stream) {
  const float* query  = (const float*)d_in[0];
  const float* keys   = (const float*)d_in[1];
  const float* values = (const float*)d_in[2];
  const float* mask   = (const float*)d_in[3];
  const float* W1     = (const float*)d_in[4];
  const float* b1     = (const float*)d_in[5];
  const float* W2     = (const float*)d_in[6];
  const float* b2     = (const float*)d_in[7];
  const float* wscore = (const float*)d_in[8];
  const float* bscore = (const float*)d_in[9];
  float* out = (float*)d_out;

  char* ws = (char*)d_ws;
  short* keysb = (short*)(ws);                   // 33,554,432 B
  short* wkt   = (short*)(ws + 33554432ull);     // 33,554,432 B
  short* w2t   = (short*)(ws + 67108864ull);     //  2,097,152 B
  float* biasb = (float*)(ws + 69206016ull);     //    262,144 B
  short* h1    = (short*)(ws + 69468160ull);     // 134,217,728 B
  float* spart = (float*)(ws + 203685888ull);    //  4,194,304 B
  float* attn  = (float*)(ws + 207880192ull);    //    262,144 B
  float* part  = (float*)(ws + 208142336ull);    //  2,097,152 B (total ~210 MB)

  k_prep_keys<<<8192, 256, 0, stream>>>(keys, keysb);
  k_prep_w2t<<<dim3(16, 16), 256, 0, stream>>>(W2, w2t);
  k_prep_wkt<<<dim3(64, 16), 256, 0, stream>>>(W1, query, b1, wkt, biasb);

  k_gemm<1><<<2048, 256, 0, stream>>>(keysb, wkt, biasb, nullptr, h1, nullptr);
  k_gemm<2><<<2048, 256, 0, stream>>>(h1, w2t, b2, wscore, nullptr, spart);

  k_softmax<<<64, 256, 0, stream>>>(spart, mask, bscore, attn);
  k_out<<<512, 256, 0, stream>>>(attn, values, part);
  k_red<<<64, 256, 0, stream>>>(part, out);
}

// Round 8
// 271.839 us; speedup vs baseline: 1.2334x; 1.0788x over previous
//
#include <hip/hip_runtime.h>

#define DEV __device__ __forceinline__

typedef __attribute__((ext_vector_type(4))) float f32x4;
typedef __attribute__((ext_vector_type(8))) short short8;
typedef __attribute__((ext_vector_type(4))) short s16x4;
typedef __attribute__((ext_vector_type(4))) float f32x4v;

DEV short f2bf(float f) {
  union { float f; unsigned u; } v; v.f = f;
  unsigned r = (v.u + 0x7FFFu + ((v.u >> 16) & 1u)) >> 16;
  return (short)r;
}

DEV void gload16(const void* g, void* l) {
  __builtin_amdgcn_global_load_lds(
      (const __attribute__((address_space(1))) void*)g,
      (__attribute__((address_space(3))) void*)l, 16, 0, 0);
}

#define BAR() __builtin_amdgcn_s_barrier()
#define LGKMW(n)                                              \
  {                                                           \
    asm volatile("s_waitcnt lgkmcnt(" #n ")" ::: "memory");   \
    __builtin_amdgcn_sched_barrier(0);                        \
  }
#define VMW(n)                                                \
  {                                                           \
    asm volatile("s_waitcnt vmcnt(" #n ")" ::: "memory");     \
    __builtin_amdgcn_sched_barrier(0);                        \
  }

// ---------------- prep kernels ----------------

__global__ __launch_bounds__(256) void k_prep_keys(const float* __restrict__ k,
                                                   short* __restrict__ o) {
  int i = (blockIdx.x * 256 + threadIdx.x) * 8;
  f32x4v v0 = *(const f32x4v*)(k + i);
  f32x4v v1 = *(const f32x4v*)(k + i + 4);
  short8 s;
  s[0] = f2bf(v0[0]); s[1] = f2bf(v0[1]); s[2] = f2bf(v0[2]); s[3] = f2bf(v0[3]);
  s[4] = f2bf(v1[0]); s[5] = f2bf(v1[1]); s[6] = f2bf(v1[2]); s[7] = f2bf(v1[3]);
  *(short8*)(o + i) = s;
}

// W2 [k 1024][n 1024] f32 -> w2f MFMA-fragment order:
// w2f[((kt*2+kh)*64 + cg)*512 + lane*8 + j] =
//   bf16( W2[kt*64 + kh*32 + (lane>>4)*8 + j][cg*16 + (lane&15)] )
__global__ __launch_bounds__(256) void k_prep_w2f(const float* __restrict__ w2,
                                                  short* __restrict__ w2f) {
  __shared__ float tile[64][65];
  const int kt = blockIdx.x, n0 = blockIdx.y * 64;
  const int a = threadIdx.x & 63, q = threadIdx.x >> 6;
#pragma unroll
  for (int i = 0; i < 16; ++i) {
    int kk = i * 4 + q;
    tile[kk][a] = w2[(size_t)(kt * 64 + kk) * 1024 + n0 + a];
  }
  __syncthreads();
  const int l = threadIdx.x & 63, cgl = threadIdx.x >> 6;
#pragma unroll
  for (int kh = 0; kh < 2; ++kh) {
    short8 v;
#pragma unroll
    for (int j = 0; j < 8; ++j)
      v[j] = f2bf(tile[kh * 32 + (l >> 4) * 8 + j][cgl * 16 + (l & 15)]);
    *(short8*)&w2f[((size_t)((kt * 2 + kh) * 64 + (n0 >> 4) + cgl)) * 512 + l * 8] = v;
  }
}

// Wk[b][d][m] = bf16( W1[256+m][d] - W1[512+m][d] + q[b][m]*W1[768+m][d] )
// stored in MFMA-fragment order per batch (512KB each):
// wktf[b*262144 + ((kt*2+kh)*64 + cg)*512 + lane*8 + j] =
//   Wk[b][d = cg*16 + (lane&15)][m = kt*64 + kh*32 + (lane>>4)*8 + j]
// + fused bias: biasb[b][d] = b1[d] + sum_m q[b][m]*(W1[m][d] + W1[512+m][d])
__global__ __launch_bounds__(256) void k_prep_wkt(const float* __restrict__ w1,
                                                  const float* __restrict__ query,
                                                  const float* __restrict__ b1,
                                                  short* __restrict__ wktf,
                                                  float* __restrict__ biasb) {
  __shared__ short tile[64][264];  // stride 264 shorts = 528B (16B-aligned rows)
  __shared__ float redm[64][4];
  const int b = blockIdx.x, d0 = blockIdx.y * 64;
  const int d = threadIdx.x & 63, mq = threadIdx.x >> 6;
  float bacc = 0.f;
#pragma unroll 4
  for (int i = 0; i < 64; ++i) {
    int m = i * 4 + mq;
    float qv = query[b * 256 + m];
    float wa = w1[(size_t)m * 1024 + d0 + d];
    float wb = w1[(size_t)(256 + m) * 1024 + d0 + d];
    float wc = w1[(size_t)(512 + m) * 1024 + d0 + d];
    float wd = w1[(size_t)(768 + m) * 1024 + d0 + d];
    tile[d][m] = f2bf(wb - wc + qv * wd);
    bacc += qv * (wa + wc);
  }
  redm[d][mq] = bacc;
  __syncthreads();
  const int l = threadIdx.x & 63, cgl = threadIdx.x >> 6;
  short* ob = wktf + (size_t)b * 262144;
#pragma unroll
  for (int kt = 0; kt < 4; ++kt)
#pragma unroll
    for (int kh = 0; kh < 2; ++kh) {
      short8 v = *(const short8*)&tile[cgl * 16 + (l & 15)]
                                      [kt * 64 + kh * 32 + (l >> 4) * 8];
      *(short8*)&ob[((size_t)((kt * 2 + kh) * 64 + (d0 >> 4) + cgl)) * 512 + l * 8] = v;
    }
  if (threadIdx.x < 64) {
    int dd = threadIdx.x;
    biasb[b * 1024 + d0 + dd] =
        redm[dd][0] + redm[dd][1] + redm[dd][2] + redm[dd][3] + b1[d0 + dd];
  }
}

// ---------------- A-in-LDS / B-from-global GEMM (TN) ----------------
// BM=128, BN=256, BK=64, 256 thr (4 waves, wave tile 128x64), launch_bounds(256,2)
// -> 2 blocks/CU. LDS: 4 x 16KB A-buffers only (B comes straight from L2 in
// fragment order, double-banked 2 tiles ahead). One barrier + 64 MFMA per K64,
// counted VMW(12) (12 = A 4 + B 8 ops per tile-group; 2 groups in flight).
// MODE 1: per-batch keys@Wk + bias, relu -> h1 (bf16).  K=256 (KT=4).
// MODE 2: h1@w2f + b2, relu, dot w_score -> score partials. K=1024 (KT=16).

template <int MODE>
__global__ __launch_bounds__(256, 2) void k_gemm(const short* __restrict__ A,
                                                 const short* __restrict__ Bf,
                                                 const float* __restrict__ bias,
                                                 const float* __restrict__ wscore,
                                                 short* __restrict__ hout,
                                                 float* __restrict__ spart) {
  __shared__ short lds[32768];  // 4 bufs x 8192 shorts (16KB each)
  constexpr int SK = (MODE == 1) ? 256 : 1024;
  constexpr int KT = (MODE == 1) ? 4 : 16;

  const int tid = threadIdx.x;
  const int bx = blockIdx.x;
  const int L = (bx & 7) * 256 + (bx >> 3);  // XCD swizzle: ct-siblings + batch co-XCD

  const short *Ab, *Bb;
  const float *biasp, *wsp = nullptr;
  short* houtp = nullptr;
  int rt, ct;
  if constexpr (MODE == 1) {
    const int b = L >> 5;
    rt = (L >> 2) & 7; ct = L & 3;
    Ab = A + ((size_t)(b * 1024 + rt * 128)) * 256;
    Bb = Bf + (size_t)b * 262144;
    biasp = bias + b * 1024 + ct * 256;
    houtp = hout + ((size_t)(b * 1024 + rt * 128)) * 1024 + ct * 256;
  } else {
    rt = L >> 2; ct = L & 3;
    Ab = A + (size_t)rt * 128 * 1024;
    Bb = Bf;
    biasp = bias + ct * 256;
    wsp = wscore + ct * 256;
  }

  // A staging: chunk s -> row = s>>3, slot = s&7, src k-chunk = slot^(row&7)
  int gA[4], dA[4];
#pragma unroll
  for (int j = 0; j < 4; ++j) {
    int s = tid + j * 256, row = s >> 3, kc = (s & 7) ^ (row & 7);
    gA[j] = row * SK + kc * 8;
    dA[j] = s * 8;
  }
  auto STAGE = [&](int kt) {
    const int bb = (kt & 3) * 8192;
#pragma unroll
    for (int j = 0; j < 4; ++j) gload16(Ab + gA[j] + kt * 64, &lds[bb + dA[j]]);
  };

  const int lane = tid & 63, l15 = lane & 15, l4 = lane >> 4, wc = tid >> 6;
  // af read: row = m*16 + l15; chunk kh*4+l4 stored at slot^(l15&7)
  const int afo0 = l15 * 64 + ((l4 ^ (l15 & 7)) * 8);
  const int afo1 = l15 * 64 + (((4 + l4) ^ (l15 & 7)) * 8);

  f32x4 acc[8][4];
#pragma unroll
  for (int m = 0; m < 8; ++m)
#pragma unroll
    for (int n = 0; n < 4; ++n) acc[m][n] = f32x4{0.f, 0.f, 0.f, 0.f};
  short8 bf[2][4][2];  // [bank][n][kh]
  short8 af[8];

#define LOADB(kt, BK_)                                                          \
  _Pragma("unroll") for (int n_ = 0; n_ < 4; ++n_) {                            \
    _Pragma("unroll") for (int kh_ = 0; kh_ < 2; ++kh_) {                       \
      bf[BK_][n_][kh_] = *(const short8*)(Bb +                                  \
          ((size_t)(((kt) * 2 + kh_) * 64 + ct * 16 + n_ * 4 + wc) << 9) +      \
          lane * 8);                                                            \
    }                                                                           \
  }

  // prologue: 2 tile-groups in flight (each = A 4 ops + B 8 ops)
  STAGE(0); LOADB(0, 0);
  STAGE(1); LOADB(1, 1);
  VMW(12);
  BAR();

#pragma unroll
  for (int t = 0; t < KT; ++t) {
    const int bb = (t & 3) * 8192;
    // kh0
#pragma unroll
    for (int m = 0; m < 8; ++m) af[m] = *(const short8*)&lds[bb + afo0 + m * 1024];
    LGKMW(0);
    __builtin_amdgcn_s_setprio(1);
#pragma unroll
    for (int m = 0; m < 8; ++m)
#pragma unroll
      for (int n = 0; n < 4; ++n)
        acc[m][n] = __builtin_amdgcn_mfma_f32_16x16x32_bf16(bf[t & 1][n][0], af[m],
                                                            acc[m][n], 0, 0, 0);
    __builtin_amdgcn_s_setprio(0);
    // kh1
#pragma unroll
    for (int m = 0; m < 8; ++m) af[m] = *(const short8*)&lds[bb + afo1 + m * 1024];
    if (t + 2 < KT) STAGE(t + 2);
    LGKMW(0);
    __builtin_amdgcn_s_setprio(1);
#pragma unroll
    for (int m = 0; m < 8; ++m)
#pragma unroll
      for (int n = 0; n < 4; ++n)
        acc[m][n] = __builtin_amdgcn_mfma_f32_16x16x32_bf16(bf[t & 1][n][1], af[m],
                                                            acc[m][n], 0, 0, 0);
    __builtin_amdgcn_s_setprio(0);
    if (t + 2 < KT) {
      LOADB(t + 2, (t & 1));
      VMW(12);       // drains group t+1 (A in LDS + B in regs), keeps t+2 in flight
    } else {
      VMW(0);        // tail: drain final group
    }
    BAR();
  }
#undef LOADB

  // ---------------- epilogue ----------------
  // C fragments: row = m*16 + l15, col(n,r2) = n*64 + wc*16 + l4*4 + r2
  if constexpr (MODE == 1) {
    float bv[4][4];
#pragma unroll
    for (int n = 0; n < 4; ++n)
#pragma unroll
      for (int r2 = 0; r2 < 4; ++r2)
        bv[n][r2] = biasp[n * 64 + wc * 16 + l4 * 4 + r2];
#pragma unroll
    for (int m = 0; m < 8; ++m) {
      int row = m * 16 + l15;
#pragma unroll
      for (int n = 0; n < 4; ++n) {
        s16x4 pk;
#pragma unroll
        for (int r2 = 0; r2 < 4; ++r2)
          pk[r2] = f2bf(fmaxf(acc[m][n][r2] + bv[n][r2], 0.f));
        *(s16x4*)&houtp[(size_t)row * 1024 + n * 64 + wc * 16 + l4 * 4] = pk;
      }
    }
  } else {
    float bv[4][4], wv[4][4];
#pragma unroll
    for (int n = 0; n < 4; ++n)
#pragma unroll
      for (int r2 = 0; r2 < 4; ++r2) {
        int c = n * 64 + wc * 16 + l4 * 4 + r2;
        bv[n][r2] = biasp[c];
        wv[n][r2] = wsp[c];
      }
    float* so = spart + ((size_t)(ct * 4 + wc) << 16) + rt * 128;
#pragma unroll
    for (int m = 0; m < 8; ++m) {
      float s = 0.f;
#pragma unroll
      for (int n = 0; n < 4; ++n)
#pragma unroll
        for (int r2 = 0; r2 < 4; ++r2)
          s += fmaxf(acc[m][n][r2] + bv[n][r2], 0.f) * wv[n][r2];
      s += __shfl_xor(s, 16);
      s += __shfl_xor(s, 32);
      if (lane < 16) so[m * 16 + l15] = s;
    }
  }
}

// ---------------- softmax + output ----------------

__global__ __launch_bounds__(256) void k_softmax(const float* __restrict__ spart,
                                                 const float* __restrict__ mask,
                                                 const float* __restrict__ bscore,
                                                 float* __restrict__ attn) {
  const int b = blockIdx.x, tid = threadIdx.x;
  __shared__ float sm[1024];
  __shared__ float red[8];
  const float bs = bscore[0];
  float lmax = -3.0e38f;
  for (int t = tid; t < 1024; t += 256) {
    float s = bs;
#pragma unroll
    for (int c = 0; c < 16; ++c) s += spart[(size_t)c * 65536 + b * 1024 + t];
    float lg = s + mask[b * 1024 + t] * (-1e9f);
    sm[t] = lg;
    lmax = fmaxf(lmax, lg);
  }
  for (int o = 32; o; o >>= 1) lmax = fmaxf(lmax, __shfl_xor(lmax, o));
  const int wid = tid >> 6, lane = tid & 63;
  if (lane == 0) red[wid] = lmax;
  __syncthreads();
  float bmax = fmaxf(fmaxf(red[0], red[1]), fmaxf(red[2], red[3]));
  float lsum = 0.f;
  for (int t = tid; t < 1024; t += 256) {
    float e = __expf(sm[t] - bmax);
    sm[t] = e;
    lsum += e;
  }
  for (int o = 32; o; o >>= 1) lsum += __shfl_xor(lsum, o);
  __syncthreads();
  if (lane == 0) red[wid] = lsum;
  __syncthreads();
  float inv = 1.0f / (red[0] + red[1] + red[2] + red[3]);
  for (int t = tid; t < 1024; t += 256) attn[b * 1024 + t] = sm[t] * inv;
}

// out partials: block (b, ts): sum t in [ts*128, ts*128+128) over all 1024 d
__global__ __launch_bounds__(256) void k_out(const float* __restrict__ attn,
                                             const float* __restrict__ values,
                                             float* __restrict__ part) {
  const int b = blockIdx.x >> 3, ts = blockIdx.x & 7;
  const int tid = threadIdx.x;
  __shared__ float at[128];
  if (tid < 128) at[tid] = attn[b * 1024 + ts * 128 + tid];
  __syncthreads();
  const float* vb = values + ((size_t)b * 1024 + ts * 128) * 1024 + tid * 4;
  f32x4 acc = {0.f, 0.f, 0.f, 0.f};
#pragma unroll 8
  for (int t = 0; t < 128; ++t) {
    f32x4v v = *(const f32x4v*)(vb + (size_t)t * 1024);
    float a = at[t];
    acc[0] += a * v[0]; acc[1] += a * v[1]; acc[2] += a * v[2]; acc[3] += a * v[3];
  }
  *(f32x4*)(part + ((size_t)(b * 8 + ts)) * 1024 + tid * 4) = acc;
}

__global__ __launch_bounds__(256) void k_red(const float* __restrict__ part,
                                             float* __restrict__ out) {
  const int b = blockIdx.x;
  const int c4 = threadIdx.x * 4;
  f32x4 s = {0.f, 0.f, 0.f, 0.f};
#pragma unroll
  for (int ts = 0; ts < 8; ++ts) {
    f32x4v v = *(const f32x4v*)(part + ((size_t)(b * 8 + ts)) * 1024 + c4);
    s[0] += v[0]; s[1] += v[1]; s[2] += v[2]; s[3] += v[3];
  }
  *(f32x4*)(out + b * 1024 + c4) = s;
}

// ---------------- launch ----------------

extern "C" void kernel_launch(void* const* d_in, const int* in_sizes, int n_in,
                              void* d_out, int out_size, void* d_ws, size_t ws_size,
                              hipStream_t stream) {
  const float* query  = (const float*)d_in[0];
  const float* keys   = (const float*)d_in[1];
  const float* values = (const float*)d_in[2];
  const float* mask   = (const float*)d_in[3];
  const float* W1     = (const float*)d_in[4];
  const float* b1     = (const float*)d_in[5];
  const float* W2     = (const float*)d_in[6];
  const float* b2     = (const float*)d_in[7];
  const float* wscore = (const float*)d_in[8];
  const float* bscore = (const float*)d_in[9];
  float* out = (float*)d_out;

  char* ws = (char*)d_ws;
  short* keysb = (short*)(ws);                   // 33,554,432 B
  short* wktf  = (short*)(ws + 33554432ull);     // 33,554,432 B (frag order, per batch)
  short* w2f   = (short*)(ws + 67108864ull);     //  2,097,152 B (frag order)
  float* biasb = (float*)(ws + 69206016ull);     //    262,144 B
  short* h1    = (short*)(ws + 69468160ull);     // 134,217,728 B
  float* spart = (float*)(ws + 203685888ull);    //  4,194,304 B
  float* attn  = (float*)(ws + 207880192ull);    //    262,144 B
  float* part  = (float*)(ws + 208142336ull);    //  2,097,152 B (total ~210 MB)

  k_prep_keys<<<8192, 256, 0, stream>>>(keys, keysb);
  k_prep_w2f<<<dim3(16, 16), 256, 0, stream>>>(W2, w2f);
  k_prep_wkt<<<dim3(64, 16), 256, 0, stream>>>(W1, query, b1, wktf, biasb);

  k_gemm<1><<<2048, 256, 0, stream>>>(keysb, wktf, biasb, nullptr, h1, nullptr);
  k_gemm<2><<<2048, 256, 0, stream>>>(h1, w2f, b2, wscore, nullptr, spart);

  k_softmax<<<64, 256, 0, stream>>>(spart, mask, bscore, attn);
  k_out<<<512, 256, 0, stream>>>(attn, values, part);
  k_red<<<64, 256, 0, stream>>>(part, out);
}